// Round 13
// baseline (257.944 us; speedup 1.0000x reference)
//
#include <hip/hip_runtime.h>
#include <hip/hip_bf16.h>

typedef float f32x2 __attribute__((ext_vector_type(2)));
typedef float f32x4 __attribute__((ext_vector_type(4)));
typedef unsigned int u32;
typedef u32 u32x4 __attribute__((ext_vector_type(4)));

// ---------------------------------------------------------------------------
// Workspace tables (ushort offsets), total 1,820,160 ushorts = 3.64 MB
// (< 4 MiB per-XCD L2 -- the R10 lesson).
// Y-PAIR X-EXTENDED (32B entries, width W+1) for all levels but sp3:
//   entry(pl,y,x): dword c = (v(y,xs,c) lo, v(y1,xs,c) hi); sample = 64
//   contiguous bytes at (y0,x0); bilinear = dot2(E1,wR, dot2(E0,wL)).
// PLAIN 16B [y][x][8ch] for sp3: 4-corner + v_perm path (wave2 only).
// ---------------------------------------------------------------------------
#define Y_SP0 0
#define Y_SP1 13056
#define Y_SP2 63744
#define Y_TP0 263424
#define Y_TP1 340992
#define Y_TP2 496128
#define Y_TP3 806400
#define P_SP3 1426944

#define G 8   // point-groups (of 8 points) per block

// blockIdx.y: 0=sp0 1=sp1 2=sp2 3=tp0 4=tp1 5=tp2 6=tp3 (y-pair), 7=sp3 (plain)
__global__ __launch_bounds__(256) void build_tabs(
    const float* __restrict__ sp0, const float* __restrict__ sp1,
    const float* __restrict__ sp2, const float* __restrict__ sp3,
    const float* __restrict__ tp0, const float* __restrict__ tp1,
    const float* __restrict__ tp2, const float* __restrict__ tp3,
    unsigned short* __restrict__ dst)
{
    int id = blockIdx.y;
    const float* src; int W, H, off; bool yp;
    switch (id) {
        case 0: src = sp0; W = 16;  H = 16;  off = Y_SP0; yp = true;  break;
        case 1: src = sp1; W = 32;  H = 32;  off = Y_SP1; yp = true;  break;
        case 2: src = sp2; W = 64;  H = 64;  off = Y_SP2; yp = true;  break;
        case 3: src = tp0; W = 100; H = 16;  off = Y_TP0; yp = true;  break;
        case 4: src = tp1; W = 100; H = 32;  off = Y_TP1; yp = true;  break;
        case 5: src = tp2; W = 100; H = 64;  off = Y_TP2; yp = true;  break;
        case 6: src = tp3; W = 100; H = 128; off = Y_TP3; yp = true;  break;
        default:src = sp3; W = 128; H = 128; off = P_SP3; yp = false; break;
    }
    int HW = W * H;
    int i = blockIdx.x * 256 + threadIdx.x;
    float v;
    if (yp) {
        int Wp = W + 1;
        int total = 3 * H * Wp * 16;
        if (i >= total) return;
        int half = i & 1;
        int c    = (i >> 1) & 7;
        int q    = i >> 4;            // pl*H*Wp + y*Wp + x
        int x  = q % Wp;
        int y  = (q / Wp) % H;
        int pl = q / (H * Wp);
        int xs = min(x, W - 1);
        int ys = half ? min(y + 1, H - 1) : y;
        v = src[(size_t)(pl * 8 + c) * HW + (size_t)ys * W + xs];
    } else {
        int total = 3 * HW * 8;
        if (i >= total) return;
        int c = i & 7;
        int q = i >> 3;
        int x  = q % W;
        int y  = (q / W) % H;
        int pl = q / HW;
        v = src[(size_t)(pl * 8 + c) * HW + (size_t)y * W + x];
    }
    __hip_bfloat16 b = __float2bfloat16(v);   // round-to-nearest
    dst[off + i] = *reinterpret_cast<unsigned short*>(&b);
}

__device__ __forceinline__ float dot2bf(u32 ab, u32 w, float acc) {
    float d;
    asm("v_dot2_f32_bf16 %0, %1, %2, %3" : "=v"(d) : "v"(ab), "v"(w), "v"(acc));
    return d;
}
__device__ __forceinline__ u32 pk_bf16(float lo, float hi) {
    u32 d;
    asm("v_cvt_pk_bf16_f32 %0, %1, %2" : "=v"(d) : "v"(lo), "v"(hi));
    return d;
}

// ---------------------------------------------------------------------------
// Main kernel: 192 threads = 24 positions x 8 points, tid = pos*8 + p,
// G=8 groups of 8 points per block, software-pipelined gathers, SINGLE
// barrier per group via double-buffered LDS bounce. Coords pipelined 2
// groups ahead (triple-buffered). Linear NT f32x4 stores (full lines).
// ---------------------------------------------------------------------------
__global__ __launch_bounds__(192) void hexplane_pipe2(
    const float* __restrict__ xyz, const float* __restrict__ t,
    const float* __restrict__ bounds, const unsigned short* __restrict__ tw,
    float* __restrict__ out, int N)
{
    __shared__ float coords[3][8][4];   // triple-buffered normalized coords
    __shared__ f32x4 lutA[24];          // sx, ox, sy, oy
    __shared__ f32x4 lutB[24];          // cx, cy, base_bytes, code
    __shared__ float ostage[2][1536];   // 12 KB double-buffered bounce

    int tid   = threadIdx.x;
    int gbase = blockIdx.x * (G * 8);   // first point of this block

    if (tid < 64) {
        // coords for groups 0 and 1
        int grp = tid >> 5, pp = (tid >> 2) & 7, comp = tid & 3;
        int n = gbase + grp * 8 + pp;
        float v = 0.0f;
        if (n < N) {
            if (comp < 3) {
                float b0 = bounds[comp], b1 = bounds[3 + comp];
                v = (xyz[(size_t)n * 3 + comp] - b0) / (b1 - b0);
            } else {
                v = t[n];
            }
        }
        coords[grp][pp][comp] = v;
    } else if (tid < 88) {
        int pos = tid - 64;
        int s = (pos < 9) ? pos + pos / 3 : (pos < 21) ? pos + 3 : 4 * (pos - 21) + 3;
        int g = s >> 2;
        int r = s & 3;
        int res = 16 << r;
        bool plain = (g < 3) && (r == 3);     // sp3
        float sx, ox, sy, oy, cx, cy;
        int base_u, Ws, selx, sely;
        if (g < 3) {
            sx = (float)res; ox = -0.5f;
            sy = (float)res; oy = -0.5f;
            cx = (float)(res - 1); cy = (float)(res - 1);
            selx = (g == 2) ? 1 : 0;
            sely = (g == 0) ? 1 : 2;
            if (plain) {
                Ws = 128;
                base_u = P_SP3 + g * 128 * 128 * 8;
            } else {
                Ws = res + 1;
                int lo = (r == 0) ? Y_SP0 : (r == 1) ? Y_SP1 : Y_SP2;
                base_u = lo + g * res * (res + 1) * 16;
            }
        } else {
            int q = g - 3;
            Ws = 101;
            sx = 99.0f; ox = 0.0f;
            sy = (float)(res - 1); oy = 0.0f;
            cx = 99.0f; cy = (float)(res - 1);
            int lo = (r == 0) ? Y_TP0 : (r == 1) ? Y_TP1 : (r == 2) ? Y_TP2 : Y_TP3;
            base_u = lo + q * res * 101 * 16;
            selx = 3;
            sely = q;
        }
        int code = Ws | (selx << 9) | (sely << 12) | (plain ? (1 << 15) : 0) | (s << 16);
        f32x4 A = { sx, ox, sy, oy };
        f32x4 B = { cx, cy, __int_as_float(base_u * 2), __int_as_float(code) };
        lutA[pos] = A;
        lutB[pos] = B;
    }
    __syncthreads();   // B0: coords[0..1], LUT visible

    int p   = tid & 7;
    int pos = tid >> 3;

    // hoisted per-thread constants
    f32x4 A = lutA[pos];
    f32x4 B = lutB[pos];
    int code  = __float_as_int(B[3]);
    int Ws    = code & 511;
    int selx  = (code >> 9) & 7;
    int sely  = (code >> 12) & 7;
    bool plain = (code >> 15) & 1;
    int s     = (code >> 16) & 31;
    u32 base_byte = (u32)__float_as_int(B[2]);
    const char* twb = (const char*)tw;

    // bounce offsets (constant across groups), float units within a buffer
    int e   = p * 24 + s;
    int k_w = p & 1;
    int bwo0 = e * 8 + (k_w ? 4 : 0);   // chunk0 slot = 0^(p&1)
    int bwo1 = e * 8 + (k_w ? 0 : 4);   // chunk1 slot = 1^(p&1)

    // readout offsets (constant across groups)
    int e0 = tid >> 1, a0 = tid & 1;
    int p0 = (e0 * 683) >> 14;          // e0/24, exact for e0<384
    int rdo0 = e0 * 8 + (a0 ^ (p0 & 1)) * 4;
    int m1 = tid + 192;
    int e1 = m1 >> 1, a1 = m1 & 1;
    int p1 = (e1 * 683) >> 14;
    int rdo1 = e1 * 8 + (a1 ^ (p1 & 1)) * 4;

    // pipeline registers
    u32 wA, wB_;
    u32x4 L0, L1, L2, L3;

    auto PREP = [&](int q) {
        int cb = q % 3;
        float fx = coords[cb][p][selx];
        float fy = coords[cb][p][sely];
        float ix = fmaf(fx, A[0], A[1]);
        float iy = fmaf(fy, A[2], A[3]);
        ix = fminf(fmaxf(ix, 0.0f), B[0]);
        iy = fminf(fmaxf(iy, 0.0f), B[1]);
        float x0f = floorf(ix), y0f = floorf(iy);
        float wx = ix - x0f, wy = iy - y0f;
        int x0 = (int)x0f, y0 = (int)y0f;
        float omx = 1.0f - wx, omy = 1.0f - wy;
        if (!plain) {
            wA  = pk_bf16(omx * omy, omx * wy);    // (w00, w10) left col
            wB_ = pk_bf16(wx * omy,  wx * wy);     // (w01, w11) right col
            u32 off = base_byte + (u32)(y0 * Ws + x0) * 32;
            L0 = *(const u32x4*)(twb + off);
            L1 = *(const u32x4*)(twb + off + 16);
            L2 = *(const u32x4*)(twb + off + 32);
            L3 = *(const u32x4*)(twb + off + 48);
        } else {
            wA  = pk_bf16(omx * omy, wx * omy);    // (w00, w01)
            wB_ = pk_bf16(omx * wy,  wx * wy);     // (w10, w11)
            int x1 = min(x0 + 1, 127), y1 = min(y0 + 1, 127);
            L0 = *(const u32x4*)(twb + base_byte + (u32)(y0 * 128 + x0) * 16);
            L1 = *(const u32x4*)(twb + base_byte + (u32)(y0 * 128 + x1) * 16);
            L2 = *(const u32x4*)(twb + base_byte + (u32)(y1 * 128 + x0) * 16);
            L3 = *(const u32x4*)(twb + base_byte + (u32)(y1 * 128 + x1) * 16);
        }
    };

    PREP(0);

    size_t total_out = (size_t)N * 192;
    size_t outbase   = (size_t)blockIdx.x * (G * 1536);
    bool safe = (outbase + (size_t)G * 1536) <= total_out;   // full block?

    for (int g = 0; g < G; ++g) {
        // consume in-flight loads
        float f[8];
        if (!plain) {
            #pragma unroll
            for (int k = 0; k < 4; ++k) {
                f[k]     = dot2bf(L2[k], wB_, dot2bf(L0[k], wA, 0.0f));
                f[4 + k] = dot2bf(L3[k], wB_, dot2bf(L1[k], wA, 0.0f));
            }
        } else {
            #pragma unroll
            for (int k = 0; k < 4; ++k) {
                u32 tA2 = __builtin_amdgcn_perm(L0[k], L1[k], 0x01000504u);
                u32 tB2 = __builtin_amdgcn_perm(L0[k], L1[k], 0x03020706u);
                u32 bA2 = __builtin_amdgcn_perm(L2[k], L3[k], 0x01000504u);
                u32 bB2 = __builtin_amdgcn_perm(L2[k], L3[k], 0x03020706u);
                f[2*k]     = dot2bf(bA2, wB_, dot2bf(tA2, wA, 0.0f));
                f[2*k + 1] = dot2bf(bB2, wB_, dot2bf(tB2, wA, 0.0f));
            }
        }

        // re-issue next group's gathers (coords[g+1] visible since last barrier)
        if (g + 1 < G) PREP(g + 1);

        // bounce write into buffer g&1 (16B-granular swizzle)
        float* ob = ostage[g & 1];
        *(f32x4*)&ob[bwo0] = *(f32x4*)&f[0];
        *(f32x4*)&ob[bwo1] = *(f32x4*)&f[4];

        // issue + stage coords for group g+2 (visible after this barrier)
        if ((g + 2 < G) && (tid < 32)) {
            int comp = tid & 3;
            int n = gbase + (g + 2) * 8 + (tid >> 2);
            float vc = 0.0f;
            if (n < N) {
                if (comp < 3) {
                    float b0 = bounds[comp], b1 = bounds[3 + comp];
                    vc = (xyz[(size_t)n * 3 + comp] - b0) / (b1 - b0);
                } else {
                    vc = t[n];
                }
            }
            coords[(g + 2) % 3][tid >> 2][comp] = vc;
        }

        __syncthreads();   // single barrier: ostage[g&1] + coords[g+2] ready

        f32x4 v0 = *(const f32x4*)&ob[rdo0];
        f32x4 v1 = *(const f32x4*)&ob[rdo1];
        size_t F0 = outbase + (size_t)g * 1536 + (size_t)tid * 4;
        size_t F1 = F0 + 768;
        if (safe) {
            __builtin_nontemporal_store(v0, (f32x4*)(out + F0));
            __builtin_nontemporal_store(v1, (f32x4*)(out + F1));
        } else {
            if (F0 + 4 <= total_out)
                __builtin_nontemporal_store(v0, (f32x4*)(out + F0));
            if (F1 + 4 <= total_out)
                __builtin_nontemporal_store(v1, (f32x4*)(out + F1));
        }
        // no second barrier: next iter writes ostage[(g+1)&1]; this buffer is
        // not rewritten until after barrier(g+1), by which time reads are done
    }
}

extern "C" void kernel_launch(void* const* d_in, const int* in_sizes, int n_in,
                              void* d_out, int out_size, void* d_ws, size_t ws_size,
                              hipStream_t stream) {
    // setup_inputs() dict order is INTERLEAVED: xyz, t, bounds,
    // sp0, tp0, sp1, tp1, sp2, tp2, sp3, tp3
    const float* xyz    = (const float*)d_in[0];
    const float* t      = (const float*)d_in[1];
    const float* bounds = (const float*)d_in[2];
    const float* sp[4]  = { (const float*)d_in[3], (const float*)d_in[5],
                            (const float*)d_in[7], (const float*)d_in[9] };
    const float* tp[4]  = { (const float*)d_in[4], (const float*)d_in[6],
                            (const float*)d_in[8], (const float*)d_in[10] };
    float* out = (float*)d_out;

    int N = in_sizes[0] / 3;
    unsigned short* tw = (unsigned short*)d_ws;

    // largest table segment: tp3 y-pair = 620,544 ushorts -> 2424 blocks
    build_tabs<<<dim3(2424, 8), 256, 0, stream>>>(
        sp[0], sp[1], sp[2], sp[3], tp[0], tp[1], tp[2], tp[3], tw);

    int blocks = (N + G * 8 - 1) / (G * 8);   // 64 points per block
    hexplane_pipe2<<<blocks, 192, 0, stream>>>(xyz, t, bounds, tw, out, N);
}

// Round 14
// 222.611 us; speedup vs baseline: 1.1587x; 1.1587x over previous
//
#include <hip/hip_runtime.h>
#include <hip/hip_bf16.h>

typedef float f32x2 __attribute__((ext_vector_type(2)));
typedef float f32x4 __attribute__((ext_vector_type(4)));
typedef unsigned int u32;
typedef u32 u32x4 __attribute__((ext_vector_type(4)));

// ---------------------------------------------------------------------------
// Workspace tables (ushort offsets), total 1,820,160 ushorts = 3.64 MB
// (< 4 MiB per-XCD L2 -- the R10 lesson).
// Y-PAIR X-EXTENDED (32B entries, width W+1) for all levels but sp3:
//   entry(pl,y,x): dword c = (v(y,xs,c) lo, v(y1,xs,c) hi); sample = 64
//   contiguous bytes at (y0,x0); bilinear = dot2(E1,wR, dot2(E0,wL)).
// PLAIN 16B [y][x][8ch] for sp3: 4-corner + v_perm path (wave2 only).
// ---------------------------------------------------------------------------
#define Y_SP0 0
#define Y_SP1 13056
#define Y_SP2 63744
#define Y_TP0 263424
#define Y_TP1 340992
#define Y_TP2 496128
#define Y_TP3 806400
#define P_SP3 1426944

#define G 4   // point-groups (of 8 points) per block

// blockIdx.y: 0=sp0 1=sp1 2=sp2 3=tp0 4=tp1 5=tp2 6=tp3 (y-pair), 7=sp3 (plain)
__global__ __launch_bounds__(256) void build_tabs(
    const float* __restrict__ sp0, const float* __restrict__ sp1,
    const float* __restrict__ sp2, const float* __restrict__ sp3,
    const float* __restrict__ tp0, const float* __restrict__ tp1,
    const float* __restrict__ tp2, const float* __restrict__ tp3,
    unsigned short* __restrict__ dst)
{
    int id = blockIdx.y;
    const float* src; int W, H, off; bool yp;
    switch (id) {
        case 0: src = sp0; W = 16;  H = 16;  off = Y_SP0; yp = true;  break;
        case 1: src = sp1; W = 32;  H = 32;  off = Y_SP1; yp = true;  break;
        case 2: src = sp2; W = 64;  H = 64;  off = Y_SP2; yp = true;  break;
        case 3: src = tp0; W = 100; H = 16;  off = Y_TP0; yp = true;  break;
        case 4: src = tp1; W = 100; H = 32;  off = Y_TP1; yp = true;  break;
        case 5: src = tp2; W = 100; H = 64;  off = Y_TP2; yp = true;  break;
        case 6: src = tp3; W = 100; H = 128; off = Y_TP3; yp = true;  break;
        default:src = sp3; W = 128; H = 128; off = P_SP3; yp = false; break;
    }
    int HW = W * H;
    int i = blockIdx.x * 256 + threadIdx.x;
    float v;
    if (yp) {
        int Wp = W + 1;
        int total = 3 * H * Wp * 16;
        if (i >= total) return;
        int half = i & 1;
        int c    = (i >> 1) & 7;
        int q    = i >> 4;            // pl*H*Wp + y*Wp + x
        int x  = q % Wp;
        int y  = (q / Wp) % H;
        int pl = q / (H * Wp);
        int xs = min(x, W - 1);
        int ys = half ? min(y + 1, H - 1) : y;
        v = src[(size_t)(pl * 8 + c) * HW + (size_t)ys * W + xs];
    } else {
        int total = 3 * HW * 8;
        if (i >= total) return;
        int c = i & 7;
        int q = i >> 3;
        int x  = q % W;
        int y  = (q / W) % H;
        int pl = q / HW;
        v = src[(size_t)(pl * 8 + c) * HW + (size_t)y * W + x];
    }
    __hip_bfloat16 b = __float2bfloat16(v);   // round-to-nearest
    dst[off + i] = *reinterpret_cast<unsigned short*>(&b);
}

__device__ __forceinline__ float dot2bf(u32 ab, u32 w, float acc) {
    float d;
    asm("v_dot2_f32_bf16 %0, %1, %2, %3" : "=v"(d) : "v"(ab), "v"(w), "v"(acc));
    return d;
}
__device__ __forceinline__ u32 pk_bf16(float lo, float hi) {
    u32 d;
    asm("v_cvt_pk_bf16_f32 %0, %1, %2" : "=v"(d) : "v"(lo), "v"(hi));
    return d;
}

// ---------------------------------------------------------------------------
// Main kernel: 192 threads = 24 positions x 8 points, tid = pos*8 + p,
// processing G=4 groups of 8 points with software-pipelined gathers:
// INTERP(g) consumes in-flight loads, PREP(g+1) immediately re-issues.
// Coords pipelined 2 groups ahead. Output via 16B-granular swizzled LDS
// bounce -> perfectly linear nontemporal f32x4 stores.
// ---------------------------------------------------------------------------
__global__ __launch_bounds__(192) void hexplane_pipe(
    const float* __restrict__ xyz, const float* __restrict__ t,
    const float* __restrict__ bounds, const unsigned short* __restrict__ tw,
    float* __restrict__ out, int N)
{
    __shared__ float coords[3][8][4];   // triple-buffered normalized coords
    __shared__ f32x4 lutA[24];          // sx, ox, sy, oy
    __shared__ f32x4 lutB[24];          // cx, cy, base_bytes, code
    __shared__ float ostage[1536];      // 6 KB bounce

    int tid   = threadIdx.x;
    int gbase = blockIdx.x * (G * 8);   // first point of this block

    if (tid < 64) {
        // coords for groups 0 and 1
        int grp = tid >> 5, pp = (tid >> 2) & 7, comp = tid & 3;
        int n = gbase + grp * 8 + pp;
        float v = 0.0f;
        if (n < N) {
            if (comp < 3) {
                float b0 = bounds[comp], b1 = bounds[3 + comp];
                v = (xyz[(size_t)n * 3 + comp] - b0) / (b1 - b0);
            } else {
                v = t[n];
            }
        }
        coords[grp][pp][comp] = v;
    } else if (tid < 88) {
        int pos = tid - 64;
        int s = (pos < 9) ? pos + pos / 3 : (pos < 21) ? pos + 3 : 4 * (pos - 21) + 3;
        int g = s >> 2;
        int r = s & 3;
        int res = 16 << r;
        bool plain = (g < 3) && (r == 3);     // sp3
        float sx, ox, sy, oy, cx, cy;
        int base_u, Ws, selx, sely;
        if (g < 3) {
            sx = (float)res; ox = -0.5f;
            sy = (float)res; oy = -0.5f;
            cx = (float)(res - 1); cy = (float)(res - 1);
            selx = (g == 2) ? 1 : 0;
            sely = (g == 0) ? 1 : 2;
            if (plain) {
                Ws = 128;
                base_u = P_SP3 + g * 128 * 128 * 8;
            } else {
                Ws = res + 1;
                int lo = (r == 0) ? Y_SP0 : (r == 1) ? Y_SP1 : Y_SP2;
                base_u = lo + g * res * (res + 1) * 16;
            }
        } else {
            int q = g - 3;
            Ws = 101;
            sx = 99.0f; ox = 0.0f;
            sy = (float)(res - 1); oy = 0.0f;
            cx = 99.0f; cy = (float)(res - 1);
            int lo = (r == 0) ? Y_TP0 : (r == 1) ? Y_TP1 : (r == 2) ? Y_TP2 : Y_TP3;
            base_u = lo + q * res * 101 * 16;
            selx = 3;
            sely = q;
        }
        int code = Ws | (selx << 9) | (sely << 12) | (plain ? (1 << 15) : 0) | (s << 16);
        f32x4 A = { sx, ox, sy, oy };
        f32x4 B = { cx, cy, __int_as_float(base_u * 2), __int_as_float(code) };
        lutA[pos] = A;
        lutB[pos] = B;
    }
    __syncthreads();   // B0: coords[0..1], LUT visible

    int p   = tid & 7;
    int pos = tid >> 3;

    // hoisted per-thread constants
    f32x4 A = lutA[pos];
    f32x4 B = lutB[pos];
    int code  = __float_as_int(B[3]);
    int Ws    = code & 511;
    int selx  = (code >> 9) & 7;
    int sely  = (code >> 12) & 7;
    bool plain = (code >> 15) & 1;
    int s     = (code >> 16) & 31;
    const char* tb = (const char*)tw + __float_as_int(B[2]);

    // bounce addresses (constant across groups)
    int e   = p * 24 + s;
    int k_w = p & 1;
    float* bw0 = &ostage[e * 8 + (k_w ? 4 : 0)];   // chunk0 slot = 0^(p&1)
    float* bw1 = &ostage[e * 8 + (k_w ? 0 : 4)];   // chunk1 slot = 1^(p&1)

    // readout addresses (constant across groups)
    int e0 = tid >> 1, a0 = tid & 1;
    int p0 = (e0 * 683) >> 14;                     // e0/24, exact for e0<384
    const float* rd0 = &ostage[e0 * 8 + (a0 ^ (p0 & 1)) * 4];
    int m1 = tid + 192;
    int e1 = m1 >> 1, a1 = m1 & 1;
    int p1 = (e1 * 683) >> 14;
    const float* rd1 = &ostage[e1 * 8 + (a1 ^ (p1 & 1)) * 4];

    // pipeline registers
    u32 wA, wB_;
    u32x4 L0, L1, L2, L3;

    auto PREP = [&](int q) {
        int cb = q % 3;
        float fx = coords[cb][p][selx];
        float fy = coords[cb][p][sely];
        float ix = fmaf(fx, A[0], A[1]);
        float iy = fmaf(fy, A[2], A[3]);
        ix = fminf(fmaxf(ix, 0.0f), B[0]);
        iy = fminf(fmaxf(iy, 0.0f), B[1]);
        float x0f = floorf(ix), y0f = floorf(iy);
        float wx = ix - x0f, wy = iy - y0f;
        int x0 = (int)x0f, y0 = (int)y0f;
        float omx = 1.0f - wx, omy = 1.0f - wy;
        if (!plain) {
            wA  = pk_bf16(omx * omy, omx * wy);    // (w00, w10) for left col
            wB_ = pk_bf16(wx * omy,  wx * wy);     // (w01, w11) for right col
            const char* ad = tb + (size_t)(y0 * Ws + x0) * 32;
            L0 = *(const u32x4*)(ad);
            L1 = *(const u32x4*)(ad + 16);
            L2 = *(const u32x4*)(ad + 32);
            L3 = *(const u32x4*)(ad + 48);
        } else {
            wA  = pk_bf16(omx * omy, wx * omy);    // (w00, w01)
            wB_ = pk_bf16(omx * wy,  wx * wy);     // (w10, w11)
            int x1 = min(x0 + 1, 127), y1 = min(y0 + 1, 127);
            L0 = *(const u32x4*)(tb + (size_t)(y0 * 128 + x0) * 16);
            L1 = *(const u32x4*)(tb + (size_t)(y0 * 128 + x1) * 16);
            L2 = *(const u32x4*)(tb + (size_t)(y1 * 128 + x0) * 16);
            L3 = *(const u32x4*)(tb + (size_t)(y1 * 128 + x1) * 16);
        }
    };

    PREP(0);

    size_t total_out = (size_t)N * 192;
    size_t outbase   = (size_t)blockIdx.x * (G * 1536);

    for (int g = 0; g < G; ++g) {
        // consume in-flight loads
        float f[8];
        if (!plain) {
            #pragma unroll
            for (int k = 0; k < 4; ++k) {
                f[k]     = dot2bf(L2[k], wB_, dot2bf(L0[k], wA, 0.0f));
                f[4 + k] = dot2bf(L3[k], wB_, dot2bf(L1[k], wA, 0.0f));
            }
        } else {
            #pragma unroll
            for (int k = 0; k < 4; ++k) {
                u32 tA2 = __builtin_amdgcn_perm(L0[k], L1[k], 0x01000504u);
                u32 tB2 = __builtin_amdgcn_perm(L0[k], L1[k], 0x03020706u);
                u32 bA2 = __builtin_amdgcn_perm(L2[k], L3[k], 0x01000504u);
                u32 bB2 = __builtin_amdgcn_perm(L2[k], L3[k], 0x03020706u);
                f[2*k]     = dot2bf(bA2, wB_, dot2bf(tA2, wA, 0.0f));
                f[2*k + 1] = dot2bf(bB2, wB_, dot2bf(tB2, wA, 0.0f));
            }
        }

        // re-issue next group's gathers (coords[g+1] visible since last barrier)
        if (g + 1 < G) PREP(g + 1);

        // bounce write (16B-granular swizzle)
        *(f32x4*)bw0 = *(f32x4*)&f[0];
        *(f32x4*)bw1 = *(f32x4*)&f[4];

        // issue coords load for group g+2
        float vc = 0.0f;
        bool doc = (g + 2 < G) && (tid < 32);
        if (doc) {
            int comp = tid & 3;
            int n = gbase + (g + 2) * 8 + (tid >> 2);
            if (n < N) {
                if (comp < 3) {
                    float b0 = bounds[comp], b1 = bounds[3 + comp];
                    vc = (xyz[(size_t)n * 3 + comp] - b0) / (b1 - b0);
                } else {
                    vc = t[n];
                }
            }
        }

        __syncthreads();   // B1: ostage ready

        f32x4 v0 = *(const f32x4*)rd0;
        f32x4 v1 = *(const f32x4*)rd1;
        size_t F0 = outbase + (size_t)g * 1536 + (size_t)tid * 4;
        size_t F1 = F0 + 768;
        if (F0 + 4 <= total_out)
            __builtin_nontemporal_store(v0, (f32x4*)(out + F0));
        if (F1 + 4 <= total_out)
            __builtin_nontemporal_store(v1, (f32x4*)(out + F1));

        if (doc) coords[(g + 2) % 3][tid >> 2][tid & 3] = vc;

        __syncthreads();   // B2: ostage reusable, coords[g+2] visible
    }
}

extern "C" void kernel_launch(void* const* d_in, const int* in_sizes, int n_in,
                              void* d_out, int out_size, void* d_ws, size_t ws_size,
                              hipStream_t stream) {
    // setup_inputs() dict order is INTERLEAVED: xyz, t, bounds,
    // sp0, tp0, sp1, tp1, sp2, tp2, sp3, tp3
    const float* xyz    = (const float*)d_in[0];
    const float* t      = (const float*)d_in[1];
    const float* bounds = (const float*)d_in[2];
    const float* sp[4]  = { (const float*)d_in[3], (const float*)d_in[5],
                            (const float*)d_in[7], (const float*)d_in[9] };
    const float* tp[4]  = { (const float*)d_in[4], (const float*)d_in[6],
                            (const float*)d_in[8], (const float*)d_in[10] };
    float* out = (float*)d_out;

    int N = in_sizes[0] / 3;
    unsigned short* tw = (unsigned short*)d_ws;

    // largest table segment: tp3 y-pair = 620,544 ushorts -> 2424 blocks
    build_tabs<<<dim3(2424, 8), 256, 0, stream>>>(
        sp[0], sp[1], sp[2], sp[3], tp[0], tp[1], tp[2], tp[3], tw);

    int blocks = (N + G * 8 - 1) / (G * 8);   // 32 points per block
    hexplane_pipe<<<blocks, 192, 0, stream>>>(xyz, t, bounds, tw, out, N);
}